// Round 7
// baseline (542.865 us; speedup 1.0000x reference)
//
#include <hip/hip_runtime.h>
#include <hip/hip_bf16.h>

typedef unsigned short u16;
typedef __attribute__((ext_vector_type(8))) short bf16x8;
typedef __attribute__((ext_vector_type(4))) float f32x4;
typedef __attribute__((ext_vector_type(2))) float f32x2;

#define MFMA16(a,b,c) __builtin_amdgcn_mfma_f32_16x16x32_bf16((a),(b),(c),0,0,0)

__device__ __forceinline__ float bf2f(u16 u){ union{unsigned int i; float f;} v; v.i=((unsigned int)u)<<16; return v.f; }
__device__ __forceinline__ u16 f2bf(float f){ union{float f; unsigned int i;} v; v.f=f; unsigned int r=v.i+0x7fffu+((v.i>>16)&1u); return (u16)(r>>16); }
__device__ __forceinline__ unsigned int pk2(float a, float b){
  __hip_bfloat162 h = __float22bfloat162_rn(make_float2(a,b));
  union{ __hip_bfloat162 h; unsigned int u; } v; v.h = h; return v.u;
}

// ============ K0: fp32 -> bf16 conversions for the 3 MFMA weights, one launch ====
__global__ __launch_bounds__(256) void kcvt3(const float* __restrict__ WE, u16* __restrict__ WEb,
                                             const float* __restrict__ Wq, u16* __restrict__ Wqb,
                                             const float* __restrict__ Wo, u16* __restrict__ Wob){
  int bid = blockIdx.x;
  const float* src; u16* dst; int base;
  if(bid < 2048){ src = WE; dst = WEb; base = bid*1024; }
  else if(bid < 2112){ src = Wq; dst = Wqb; base = (bid-2048)*1024; }
  else { src = Wo; dst = Wob; base = (bid-2112)*1024; }
  int i = base + threadIdx.x*4;
  float4 v = *(const float4*)(src + i);
  ushort4 o; o.x = f2bf(v.x); o.y = f2bf(v.y); o.z = f2bf(v.z); o.w = f2bf(v.w);
  *(ushort4*)(dst + i) = o;
}

// ================= K1: qkvvT[b][oc][n] = sum_c Wq[oc][c]*x[b][c][n] (MFMA) =========
#define K1PAD 136
__global__ __launch_bounds__(256) void k1_qkvv(const float* __restrict__ x, const u16* __restrict__ Wqb, u16* __restrict__ qkvvT){
  __shared__ u16 lB[128*K1PAD];
  const int tile = blockIdx.x;            // b*256 + token tile
  const int b  = tile >> 8;
  const int n0 = (tile & 255) << 7;
  const int tid = threadIdx.x;
  const float* xb = x + (size_t)b*128*32768;
  {
    const int cb = (tid >> 4) << 1;       // even channel 0..30
    const int m  = tid & 15;
    const int t8 = m << 3;                // 8-token block
    const int swz = (m & 3) << 3;         // rotation amount (u16 units)
    unsigned int* basep = (unsigned int*)lB;
    #pragma unroll
    for(int r=0;r<4;++r){
      const int c = cb + (r<<5);
      const float4* p0 = (const float4*)(xb + (size_t)c*32768 + n0 + t8);
      const float4* p1 = (const float4*)(xb + (size_t)(c+1)*32768 + n0 + t8);
      float4 a0 = p0[0], a1 = p0[1];
      float4 b0 = p1[0], b1 = p1[1];
      const int rot = (swz + c) & 127;    // rotation keeps everything inside the row
      int di = t8*68 + (rot>>1);
      basep[di      ] = pk2(a0.x, b0.x);
      basep[di+  68 ] = pk2(a0.y, b0.y);
      basep[di+ 136 ] = pk2(a0.z, b0.z);
      basep[di+ 204 ] = pk2(a0.w, b0.w);
      basep[di+ 272 ] = pk2(a1.x, b1.x);
      basep[di+ 340 ] = pk2(a1.y, b1.y);
      basep[di+ 408 ] = pk2(a1.z, b1.z);
      basep[di+ 476 ] = pk2(a1.w, b1.w);
    }
  }
  __syncthreads();
  const int wave = tid >> 6, lane = tid & 63;
  const int wm = (wave & 1) << 6;   // oc half
  const int wn = (wave >> 1) << 6;  // token half
  const int lm = lane & 15, lq = lane >> 4;
  u16* outb = qkvvT + (size_t)b*512*32768;
  for(int s=0;s<4;++s){
    const int oc0 = s << 7;
    f32x4 acc[4][4] = {};
    const u16* Arow = Wqb + (oc0 + wm + lm)*128 + lq*8;
    #pragma unroll
    for(int ks=0; ks<4; ++ks){
      bf16x8 af[4], bfr[4];
      #pragma unroll
      for(int mt=0;mt<4;++mt) af[mt] = *(const bf16x8*)(Arow + mt*2048 + ks*32);
      #pragma unroll
      for(int nt=0;nt<4;++nt){
        const int tr = wn + nt*16 + lm;
        const int rot = ((((tr>>3)&3)<<3) + ks*32 + lq*8) & 127;
        bfr[nt] = *(const bf16x8*)(&lB[tr*K1PAD + rot]);
      }
      #pragma unroll
      for(int mt=0;mt<4;++mt)
        #pragma unroll
        for(int nt=0;nt<4;++nt)
          acc[mt][nt] = MFMA16(af[mt], bfr[nt], acc[mt][nt]);
    }
    #pragma unroll
    for(int mt=0;mt<4;++mt){
      const int ocr = oc0 + wm + mt*16 + lq*4;
      #pragma unroll
      for(int nt=0;nt<4;++nt){
        const int n = n0 + wn + nt*16 + lm;
        #pragma unroll
        for(int r=0;r<4;++r) outb[(size_t)(ocr+r)*32768 + n] = f2bf(acc[mt][nt][r]);
      }
    }
  }
}

// ============ K2: fold fc(1x1) into depthwise-grouped conv weights ===============
// W_eff2 layout: [g 32][j 16][k 27][ol 4][dup 2] fp32 — each weight DUPLICATED
// (w,w) so the conv role's packed-FP32 FMA gets a ready (w,w) operand pair.
__global__ void k2_weff(const float* __restrict__ Wdep, const float* __restrict__ Wfc,
                        const float* __restrict__ bdep, const float* __restrict__ bfc,
                        float* __restrict__ W_eff2, float* __restrict__ bias_eff){
  int idx = blockIdx.x*256 + threadIdx.x;
  if(idx < 55296){
    int ol = idx & 3;
    int k  = (idx >> 2) % 27;
    int j  = (idx / 108) & 15;
    int g  = idx / 1728;
    int oc = g*4 + ol;
    float s = 0.f;
    for(int o=0;o<16;++o) s += Wdep[(oc*16 + o)*27 + k] * Wfc[o*16 + j];
    W_eff2[idx*2] = s;
    W_eff2[idx*2+1] = s;
  }
  if(idx < 128){
    float s = bdep[idx];
    for(int o=0;o<16;++o){
      float wsum = 0.f;
      for(int k=0;k<27;++k) wsum += Wdep[(idx*16 + o)*27 + k];
      s += wsum * bfc[o];  // b_fc == 0 in this problem (boundary fold vacuous)
    }
    bias_eff[idx] = s;
  }
}

// ============ KMEGA: kconv + k2b(norms) + k3(proj) + k4(gram) in ONE launch ======
// kconv role now PACKED-FP32: acc2[4 oc][4 xi-pairs] f32x2; inner loop in v2f32
// ext-vector arithmetic -> backend selects v_pk_fma_f32 (gfx90a+ packed fp32,
// 2x rate — MI355X's 157.3 TF fp32 IS the packed rate). kx=0/2 input pairs fall
// out of the float4 loads aligned; kx=1 needs 4 constructed pairs/row. Weights
// come pre-duplicated (w,w) from W_eff2. Staging/geometry/barriers byte-preserved.
#define CSX 36
#define CSZ 360            // 10*CSX
__global__ __launch_bounds__(256,6) void kmega(const u16* __restrict__ qkvvT, const float* __restrict__ W_eff2,
                                               const float* __restrict__ bias_eff, u16* __restrict__ convo,
                                               const u16* __restrict__ WEb, float* __restrict__ kp,
                                               float* __restrict__ vp, float* __restrict__ G,
                                               float* __restrict__ invn){
  __shared__ float lf[10*CSZ];   // 14,400 B (kconv role)
  __shared__ float wsum[4];      // k2b role
  const int bid = blockIdx.x;
  const int gq = bid / 15, rr = bid - gq*15;
  const int tid = threadIdx.x;

  if(rr < 8){
    // ---------------- kconv role (cidx 0..2047), packed fp32 ----------------
    const int cidx = gq*8 + rr;
    const int gx = cidx & 15, g = (cidx>>4)&31, b = cidx>>9;
    const int zt = gx >> 2, yt = gx & 3;
    const int z0 = zt << 3, y0 = yt << 3;
    const int lz = tid >> 5;                // output z (0..7)
    const int vy = (tid >> 2) & 7;
    const int x0 = (tid & 3) << 3;
    f32x2 acc2[4][4];
    #pragma unroll
    for(int oc=0;oc<4;++oc)
      #pragma unroll
      for(int xp=0;xp<4;++xp) acc2[oc][xp] = (f32x2){0.f, 0.f};
    const u16* qb = qkvvT + (size_t)b*512*32768;
    const int sz = tid / 10, sy = tid - sz*10;
    const int gz = z0 + sz - 1, gy = y0 + sy - 1;
    const bool srow_ok = (tid < 100) && ((unsigned)gz < 32u) && ((unsigned)gy < 32u);
    float2* d2 = (float2*)&lf[sz*CSZ + sy*CSX];
    const float* Wgbase = W_eff2 + (size_t)(g*16)*216;

    for(int p=0;p<16;++p){
      __syncthreads();   // previous pass compute done
      if(tid < 100){
        if(srow_ok){
          const u16* src = qb + ((size_t)(p*32 + g))*32768 + gz*1024 + gy*32;
          float carry = 0.f;
          #pragma unroll
          for(int q=0;q<4;++q){
            bf16x8 v = *(const bf16x8*)(src + q*8);
            float w0=bf2f((u16)v[0]), w1=bf2f((u16)v[1]), w2=bf2f((u16)v[2]), w3=bf2f((u16)v[3]);
            float w4=bf2f((u16)v[4]), w5=bf2f((u16)v[5]), w6=bf2f((u16)v[6]), w7=bf2f((u16)v[7]);
            d2[q*4+0] = make_float2(carry, w0);
            d2[q*4+1] = make_float2(w1, w2);
            d2[q*4+2] = make_float2(w3, w4);
            d2[q*4+3] = make_float2(w5, w6);
            carry = w7;
          }
          d2[16] = make_float2(carry, 0.f);
        } else {
          #pragma unroll
          for(int i=0;i<17;++i) d2[i] = make_float2(0.f, 0.f);
        }
      }
      __syncthreads();
      const float* Wg = Wgbase + p*216;    // [kz3][ky3][kx3][oc4][dup2], wave-uniform
      #pragma unroll
      for(int dy=0;dy<3;++dy){
        #pragma unroll
        for(int dz=0;dz<3;++dz){
          const float* row = &lf[(lz+dz)*CSZ + (vy+dy)*CSX + x0];
          float4 fa = *(const float4*)(row);
          float4 fb = *(const float4*)(row+4);
          float2 fc = *(const float2*)(row+8);
          f32x2 fp0 = {fa.x, fa.y}, fp1 = {fa.z, fa.w}, fp2 = {fb.x, fb.y},
                fp3 = {fb.z, fb.w}, fp4 = {fc.x, fc.y};
          f32x2 fs0 = {fa.y, fa.z}, fs1 = {fa.w, fb.x}, fs2 = {fb.y, fb.z},
                fs3 = {fb.w, fc.x};
          const f32x2* Wb = (const f32x2*)Wg + (dz*3+dy)*12;  // [kx3][oc4] pairs
          f32x2 fpl[4] = {fp0, fp1, fp2, fp3};
          f32x2 fsl[4] = {fs0, fs1, fs2, fs3};
          f32x2 fph[4] = {fp1, fp2, fp3, fp4};
          #pragma unroll
          for(int xp=0;xp<4;++xp){
            f32x2 f0 = fpl[xp], f1 = fsl[xp], f2 = fph[xp];
            acc2[0][xp] += Wb[0]*f0;  acc2[1][xp] += Wb[1]*f0;
            acc2[2][xp] += Wb[2]*f0;  acc2[3][xp] += Wb[3]*f0;
            acc2[0][xp] += Wb[4]*f1;  acc2[1][xp] += Wb[5]*f1;
            acc2[2][xp] += Wb[6]*f1;  acc2[3][xp] += Wb[7]*f1;
            acc2[0][xp] += Wb[8]*f2;  acc2[1][xp] += Wb[9]*f2;
            acc2[2][xp] += Wb[10]*f2; acc2[3][xp] += Wb[11]*f2;
          }
        }
      }
    }
    const float4 bi = *(const float4*)(bias_eff + g*4);  // wave-uniform -> s_load
    const int nb = (z0 + lz)*1024 + (y0+vy)*32 + x0;
    u16* ob = convo + ((size_t)b*32768 + nb)*128 + g*4;
    #pragma unroll
    for(int xi=0;xi<8;++xi){
      unsigned long long pk = (unsigned long long)f2bf(acc2[0][xi>>1][xi&1] + bi.x)
                            | ((unsigned long long)f2bf(acc2[1][xi>>1][xi&1] + bi.y) << 16)
                            | ((unsigned long long)f2bf(acc2[2][xi>>1][xi&1] + bi.z) << 32)
                            | ((unsigned long long)f2bf(acc2[3][xi>>1][xi&1] + bi.w) << 48);
      *(unsigned long long*)(ob + (size_t)xi*128) = pk;
    }
    return;
  }

  const int oidx = gq*7 + (rr - 8);   // 0..1791
  if(oidx < 512){
    // ---------------- k3 role: k_proj / v_SA_proj ----------------
    const int kc = oidx & 31;
    const int b  = (oidx >> 5) & 3;
    const int zz = oidx >> 7;             // 0..3
    const int ts = zz >> 1;
    const int rh = (zz & 1) << 6;
    const int wave = tid >> 6, lane = tid & 63;
    const int lm = lane & 15, lq = lane >> 4;
    const int coff = ts ? 384 : 128;
    const u16* Arow = qkvvT + ((size_t)b*512 + coff + rh + wave*16 + lm)*32768 + kc*1024 + lq*8;
    f32x4 acc[4] = {};
    for(int ks=0; ks<32; ++ks){
      bf16x8 af = *(const bf16x8*)(Arow + ks*32);
      #pragma unroll
      for(int nt=0;nt<4;++nt){
        bf16x8 bfr = *(const bf16x8*)(WEb + (size_t)(nt*16 + lm)*32768 + kc*1024 + ks*32 + lq*8);
        acc[nt] = MFMA16(af, bfr, acc[nt]);
      }
    }
    float* out = (ts ? vp : kp) + (size_t)b*128*64;
    const int r0 = rh + wave*16 + lq*4;
    #pragma unroll
    for(int nt=0;nt<4;++nt){
      const int p = nt*16 + lm;
      #pragma unroll
      for(int r=0;r<4;++r) atomicAdd(&out[(r0+r)*64 + p], acc[nt][r]);
    }
  } else if(oidx < 768){
    // ---------------- k4 role: Gram, one kc chunk per wave ----------------
    const int idx2 = oidx - 512;          // 0..255
    const int h = idx2 & 3, b = (idx2>>2)&3, kcg = idx2 >> 4;   // kcg 0..15
    const int wave = tid >> 6, lane = tid & 63;
    const int kc = kcg*4 + wave;          // 0..63
    const int lm = lane & 15, lq = lane >> 4;
    const u16* qb = qkvvT + ((size_t)b*512 + h*32)*32768 + kc*512 + lq*8;
    const u16* kb = qb + (size_t)128*32768;
    f32x4 acc[2][2] = {};
    for(int ks=0; ks<16; ++ks){
      bf16x8 af[2], bfr[2];
      af[0]  = *(const bf16x8*)(qb + (size_t)lm*32768 + ks*32);
      af[1]  = *(const bf16x8*)(qb + (size_t)(16+lm)*32768 + ks*32);
      bfr[0] = *(const bf16x8*)(kb + (size_t)lm*32768 + ks*32);
      bfr[1] = *(const bf16x8*)(kb + (size_t)(16+lm)*32768 + ks*32);
      #pragma unroll
      for(int mt=0;mt<2;++mt)
        #pragma unroll
        for(int nt=0;nt<2;++nt) acc[mt][nt] = MFMA16(af[mt], bfr[nt], acc[mt][nt]);
    }
    float* Gb = G + (size_t)(b*4 + h)*1024;
    #pragma unroll
    for(int mt=0;mt<2;++mt)
      #pragma unroll
      for(int nt=0;nt<2;++nt)
        #pragma unroll
        for(int r=0;r<4;++r){
          int d = mt*16 + lq*4 + r, e = nt*16 + lm;
          atomicAdd(&Gb[d*32 + e], acc[mt][nt][r]);
        }
  } else {
    // ---------------- k2b role: inverse l2 norms ----------------
    const int idx4 = oidx - 768;          // 0..1023
    const int b = idx4 >> 8, c = idx4 & 255;
    const u16* row = qkvvT + ((size_t)b*512 + c)*32768;
    float s = 0.f;
    for(int n = tid*8; n < 32768; n += 2048){
      bf16x8 v = *(const bf16x8*)(row + n);
      #pragma unroll
      for(int j=0;j<8;++j){ float f = bf2f((u16)v[j]); s += f*f; }
    }
    for(int off=32; off; off>>=1) s += __shfl_down(s, off, 64);
    if((tid & 63)==0) wsum[tid>>6] = s;
    __syncthreads();
    if(tid==0){
      float t = wsum[0]+wsum[1]+wsum[2]+wsum[3];
      invn[idx4] = 1.0f / fmaxf(sqrtf(t), 1e-12f);
    }
  }
}

// ============ K4b: scale+softmax(attn_CA) then M2 = W_out2 * attn_CA =============
__global__ __launch_bounds__(256) void k4b_softmax_m2(const float* __restrict__ G, const float* __restrict__ invn,
                                                      const float* __restrict__ temp, const float* __restrict__ Wout2,
                                                      u16* __restrict__ M2){
  const int b = blockIdx.x >> 2, h = blockIdx.x & 3;
  __shared__ float A[32][33];
  const float* Gb = G + (size_t)(b*4 + h)*1024;
  const float* inb = invn + b*256;
  const float th = temp[h];
  const int tid = threadIdx.x;
  if(tid < 32){
    const int d = tid;
    const float iq = inb[h*32 + d];
    float row[32]; float mx = -1e30f;
    #pragma unroll
    for(int e=0;e<32;++e){
      float v = Gb[d*32+e] * iq * inb[128 + h*32 + e] * th;
      row[e] = v; mx = fmaxf(mx, v);
    }
    float s = 0.f;
    #pragma unroll
    for(int e=0;e<32;++e){ float ee = __expf(row[e]-mx); row[e] = ee; s += ee; }
    const float rs = 1.0f/s;
    #pragma unroll
    for(int e=0;e<32;++e) A[d][e] = row[e]*rs;
  }
  __syncthreads();
  for(int o = tid; o < 2048; o += 256){
    const int j = o >> 5, e = o & 31;
    float s = 0.f;
    #pragma unroll
    for(int d=0;d<32;++d) s += Wout2[j*128 + h*32 + d] * A[d][e];
    M2[((size_t)b*64 + j)*128 + h*32 + e] = f2bf(s);
  }
}

// ============ K5 v3: Linformer attention via MFMA ================================
__global__ __launch_bounds__(256) void k5_xsa(const u16* __restrict__ qkvvT, const float* __restrict__ kp,
                                              const float* __restrict__ vp, const float* __restrict__ invn,
                                              const float* __restrict__ bE, const float* __restrict__ temp2,
                                              u16* __restrict__ xsa){
  __shared__ __align__(16) u16 L[14336];
  __shared__ float liqt[32];
  u16* lkAh = L;            // [64][40] : kp^T + bE, hi
  u16* lkAl = L + 2560;     // lo
  u16* lvAh = L + 5120;     // [32][72] : vp + bE, hi
  u16* lvAl = L + 7424;     // lo
  u16* Pl   = L + 9728;     // [4 waves][16][72] per-wave P bounce
  const int b = blockIdx.z, h = blockIdx.y;
  const int tid = threadIdx.x;
  const float t2 = temp2[h];
  {  // stage lkA = kp^T + bE (hi/lo)
    const int p = tid >> 2, d8 = (tid & 3) << 3;
    const float be = bE[p];
    const float* kpb = kp + ((size_t)b*128 + h*32)*64;
    #pragma unroll
    for(int j=0;j<8;++j){
      float v = kpb[(size_t)(d8+j)*64 + p] + be;
      u16 hi = f2bf(v);
      lkAh[p*40 + d8 + j] = hi;
      lkAl[p*40 + d8 + j] = f2bf(v - bf2f(hi));
    }
  }
  {  // stage lvA = vp + bE (hi/lo)
    const int d = tid >> 3, p8 = (tid & 7) << 3;
    const float* vpb = vp + ((size_t)b*128 + h*32)*64;
    #pragma unroll
    for(int j=0;j<8;++j){
      float v = vpb[(size_t)d*64 + p8 + j] + bE[p8+j];
      u16 hi = f2bf(v);
      lvAh[d*72 + p8 + j] = hi;
      lvAl[d*72 + p8 + j] = f2bf(v - bf2f(hi));
    }
  }
  if(tid < 32) liqt[tid] = invn[b*256 + h*32 + tid] * t2;   // fold temp2 into qn
  __syncthreads();
  const int wave = tid >> 6, lane = tid & 63;
  const int lm = lane & 15, lq = lane >> 4;
  const int tokw = blockIdx.x*256 + wave*64;
  const u16* qb = qkvvT + ((size_t)b*512 + h*32)*32768;
  float iq[8];
  #pragma unroll
  for(int j=0;j<8;++j) iq[j] = liqt[lq*8+j];
  u16* PW = Pl + wave*1152 + lm*72;
  u16* ob = xsa + (((size_t)b*4 + h)*32)*32768;
  for(int nt=0; nt<4; ++nt){
    const int tok = tokw + nt*16 + lm;
    union { u16 u[8]; bf16x8 v; } qh, ql;
    #pragma unroll
    for(int j=0;j<8;++j){
      float qv = bf2f(qb[(size_t)(lq*8+j)*32768 + tok]) * iq[j];
      u16 hi = f2bf(qv);
      qh.u[j] = hi;
      ql.u[j] = f2bf(qv - bf2f(hi));
    }
    f32x4 accS[4];
    #pragma unroll
    for(int mt=0;mt<4;++mt){
      bf16x8 Ah = *(const bf16x8*)(lkAh + (mt*16+lm)*40 + lq*8);
      bf16x8 Al = *(const bf16x8*)(lkAl + (mt*16+lm)*40 + lq*8);
      f32x4 a = {};
      a = MFMA16(Ah, qh.v, a);
      a = MFMA16(Ah, ql.v, a);
      a = MFMA16(Al, qh.v, a);
      accS[mt] = a;
    }
    float mx = -1e30f;
    #pragma unroll
    for(int mt=0;mt<4;++mt)
      mx = fmaxf(mx, fmaxf(fmaxf(accS[mt][0],accS[mt][1]), fmaxf(accS[mt][2],accS[mt][3])));
    mx = fmaxf(mx, __shfl_xor(mx,16));
    mx = fmaxf(mx, __shfl_xor(mx,32));
    float pexp[4][4];
    float sum = 0.f;
    #pragma unroll
    for(int mt=0;mt<4;++mt)
      #pragma unroll
      for(int r=0;r<4;++r){ float e = __expf(accS[mt][r]-mx); pexp[mt][r]=e; sum+=e; }
    sum += __shfl_xor(sum,16);
    sum += __shfl_xor(sum,32);
    const float rinv = 1.0f/sum;
    #pragma unroll
    for(int mt=0;mt<4;++mt){
      *(unsigned int*)(PW + mt*16 + lq*4)     = pk2(pexp[mt][0], pexp[mt][1]);
      *(unsigned int*)(PW + mt*16 + lq*4 + 2) = pk2(pexp[mt][2], pexp[mt][3]);
    }
    f32x4 accO[2] = {};
    #pragma unroll
    for(int ks=0;ks<2;++ks){
      bf16x8 Pb = *(const bf16x8*)(PW + ks*32 + lq*8);
      #pragma unroll
      for(int mt=0;mt<2;++mt){
        bf16x8 Avh = *(const bf16x8*)(lvAh + (mt*16+lm)*72 + ks*32 + lq*8);
        bf16x8 Avl = *(const bf16x8*)(lvAl + (mt*16+lm)*72 + ks*32 + lq*8);
        accO[mt] = MFMA16(Avh, Pb, accO[mt]);
        accO[mt] = MFMA16(Avl, Pb, accO[mt]);
      }
    }
    #pragma unroll
    for(int mt=0;mt<2;++mt)
      #pragma unroll
      for(int r=0;r<4;++r)
        ob[(size_t)(mt*16+lq*4+r)*32768 + tok] = f2bf(accO[mt][r]*rinv);
  }
}

// ============ K6: output assembly (SA gather-GEMM + CA GEMM + conv + rates), fp32 out
#define K6PAD 136
__global__ __launch_bounds__(256) void k6_out(const u16* __restrict__ qkvvT, const u16* __restrict__ xsa,
                                              const u16* __restrict__ conv, const u16* __restrict__ M2,
                                              const u16* __restrict__ Woutb, const float* __restrict__ bout,
                                              const float* __restrict__ bout2, const float* __restrict__ rate,
                                              const float* __restrict__ rate2, float* __restrict__ out){
  __shared__ u16 lA[128*K6PAD];
  const int tile = blockIdx.x;
  const int b  = tile >> 8;
  const int n0 = (tile & 255) << 7;
  const int tid = threadIdx.x;
  const int hh = (n0 >> 8) & 3;   // constant per 128-token tile
  const int dh = n0 >> 10;
  // ---- phase A: stage scrambled x_SA segment (contiguous!) -> lA[tok][c']
  const u16* xseg = xsa + (((size_t)b*4 + hh)*32 + dh)*32768 + ((size_t)(n0 & 255) << 7);
  {
    const int r = tid >> 1, off = (tid & 1) << 6;
    const u16* src = xseg + r*128 + off;
    u16* dst = &lA[r*K6PAD + off];
    #pragma unroll
    for(int q=0;q<8;++q) *(bf16x8*)(dst + q*8) = *(const bf16x8*)(src + q*8);
  }
  __syncthreads();
  const int wave = tid >> 6, lane = tid & 63;
  const int lm = lane & 15, lq = lane >> 4;
  f32x4 accS[2][4] = {};
  #pragma unroll
  for(int ks=0;ks<4;++ks){
    bf16x8 a0 = *(const bf16x8*)(&lA[(wave*32 + lm)*K6PAD + ks*32 + lq*8]);
    bf16x8 a1 = *(const bf16x8*)(&lA[(wave*32 + 16 + lm)*K6PAD + ks*32 + lq*8]);
    #pragma unroll
    for(int nt=0;nt<4;++nt){
      bf16x8 bw = *(const bf16x8*)(Woutb + (nt*16 + lm)*128 + ks*32 + lq*8);
      accS[0][nt] = MFMA16(a0, bw, accS[0][nt]);
      accS[1][nt] = MFMA16(a1, bw, accS[1][nt]);
    }
  }
  __syncthreads();
  // ---- phase B: stage v_CA tile transposed -> lA[tok][c'']
  {
    const int cb = tid >> 4, t8 = (tid & 15) << 3;
    const u16* vb = qkvvT + ((size_t)b*512 + 256)*32768 + n0;
    #pragma unroll
    for(int r2=0;r2<8;++r2){
      int c = cb + (r2<<4);
      bf16x8 v = *(const bf16x8*)(vb + (size_t)c*32768 + t8);
      #pragma unroll
      for(int j=0;j<8;++j) lA[(t8+j)*K6PAD + c] = (u16)v[j];
    }
  }
  __syncthreads();
  f32x4 accC[2][4] = {};
  #pragma unroll
  for(int ks=0;ks<4;++ks){
    bf16x8 a0 = *(const bf16x8*)(&lA[(wave*32 + lm)*K6PAD + ks*32 + lq*8]);
    bf16x8 a1 = *(const bf16x8*)(&lA[(wave*32 + 16 + lm)*K6PAD + ks*32 + lq*8]);
    #pragma unroll
    for(int nt=0;nt<4;++nt){
      bf16x8 bm = *(const bf16x8*)(M2 + ((size_t)b*64 + nt*16 + lm)*128 + ks*32 + lq*8);
      accC[0][nt] = MFMA16(a0, bm, accC[0][nt]);
      accC[1][nt] = MFMA16(a1, bm, accC[1][nt]);
    }
  }
  const float rt = rate[0], rt2 = rate2[0];
  float* ob = out + ((size_t)b*32768 + n0)*128;
  const u16* cbp = conv + ((size_t)b*32768 + n0)*128;
  #pragma unroll
  for(int mt=0;mt<2;++mt){
    #pragma unroll
    for(int r=0;r<4;++r){
      const int tok = wave*32 + mt*16 + lq*4 + r;
      #pragma unroll
      for(int nt=0;nt<4;++nt){
        const int j = nt*16 + lm;
        float sa = accS[mt][nt][r] + bout[j];
        float ca = accC[mt][nt][r] + bout2[j];
        float c1 = bf2f(cbp[(size_t)tok*128 + j]);
        float c2 = bf2f(cbp[(size_t)tok*128 + 64 + j]);
        ob[(size_t)tok*128 + j]      = rt*sa + rt2*c1;
        ob[(size_t)tok*128 + 64 + j] = rt*ca + rt2*c2;
      }
    }
  }
}

extern "C" void kernel_launch(void* const* d_in, const int* in_sizes, int n_in,
                              void* d_out, int out_size, void* d_ws, size_t ws_size,
                              hipStream_t stream){
  const float* x     = (const float*)d_in[0];
  const float* Wq    = (const float*)d_in[1];
  const float* Wfc   = (const float*)d_in[2];
  const float* bfc   = (const float*)d_in[3];
  const float* Wdep  = (const float*)d_in[4];
  const float* bdep  = (const float*)d_in[5];
  const float* WE    = (const float*)d_in[6];
  const float* bE    = (const float*)d_in[7];
  const float* temp  = (const float*)d_in[8];
  const float* temp2 = (const float*)d_in[9];
  const float* rate  = (const float*)d_in[10];
  const float* rate2 = (const float*)d_in[11];
  const float* Wout  = (const float*)d_in[12];
  const float* bout  = (const float*)d_in[13];
  const float* Wout2 = (const float*)d_in[14];
  const float* bout2 = (const float*)d_in[15];
  float* outp = (float*)d_out;

  char* w = (char*)d_ws;
  size_t off = 0;
  auto alloc = [&](size_t bytes)->char*{ char* p = w + off; off += (bytes + 255) & ~(size_t)255; return p; };
  u16*   qkvvT  = (u16*)  alloc((size_t)4*512*32768*2);   // 134 MB, channel-major
  u16*   xsa    = (u16*)  alloc((size_t)4*4*32*32768*2);  // 33.5 MB
  u16*   convb  = (u16*)  alloc((size_t)4*32768*128*2);   // 33.5 MB, token-major
  float* W_eff2 = (float*)alloc(110592*4);                // duplicated (w,w) pairs
  float* biasef = (float*)alloc(128*4);
  float* invn   = (float*)alloc(1024*4);
  float* kp     = (float*)alloc(32768*4);
  float* vp     = (float*)alloc(32768*4);
  float* G      = (float*)alloc(16384*4);
  u16*   M2     = (u16*)  alloc(32768*2);
  u16*   WEb    = (u16*)  alloc((size_t)2097152*2);       // bf16 copies of MFMA weights
  u16*   Wqb    = (u16*)  alloc(65536*2);
  u16*   Woutb  = (u16*)  alloc(8192*2);

  // zero the fp32 atomic-accumulation buffers (kp|vp|G are contiguous)
  hipMemsetAsync(kp, 0, (size_t)(32768+32768+16384)*4, stream);

  kcvt3         <<<2120,          256, 0, stream>>>(WE, WEb, Wq, Wqb, Wout, Woutb);
  k1_qkvv       <<<1024,          256, 0, stream>>>(x, Wqb, qkvvT);
  k2_weff       <<<216,           256, 0, stream>>>(Wdep, Wfc, bdep, bfc, W_eff2, biasef);
  kmega         <<<3840,          256, 0, stream>>>(qkvvT, W_eff2, biasef, convb, WEb, kp, vp, G, invn);
  k4b_softmax_m2<<<16,            256, 0, stream>>>(G, invn, temp, Wout2, M2);
  k5_xsa        <<<dim3(128,4,4), 256, 0, stream>>>(qkvvT, kp, vp, invn, bE, temp2, xsa);
  k6_out        <<<1024,          256, 0, stream>>>(qkvvT, xsa, convb, M2, Woutb, bout, bout2, rate, rate2, outp);
}

// Round 10
// 509.540 us; speedup vs baseline: 1.0654x; 1.0654x over previous
//
#include <hip/hip_runtime.h>
#include <hip/hip_bf16.h>

typedef unsigned short u16;
typedef __attribute__((ext_vector_type(8))) short bf16x8;
typedef __attribute__((ext_vector_type(4))) float f32x4;
typedef __attribute__((ext_vector_type(2))) float f32x2;

#define MFMA16(a,b,c) __builtin_amdgcn_mfma_f32_16x16x32_bf16((a),(b),(c),0,0,0)

__device__ __forceinline__ float bf2f(u16 u){ union{unsigned int i; float f;} v; v.i=((unsigned int)u)<<16; return v.f; }
__device__ __forceinline__ u16 f2bf(float f){ union{float f; unsigned int i;} v; v.f=f; unsigned int r=v.i+0x7fffu+((v.i>>16)&1u); return (u16)(r>>16); }
__device__ __forceinline__ unsigned int pk2(float a, float b){
  __hip_bfloat162 h = __float22bfloat162_rn(make_float2(a,b));
  union{ __hip_bfloat162 h; unsigned int u; } v; v.h = h; return v.u;
}

// ============ K0: fp32 -> bf16 conversions for the 3 MFMA weights, one launch ====
__global__ __launch_bounds__(256) void kcvt3(const float* __restrict__ WE, u16* __restrict__ WEb,
                                             const float* __restrict__ Wq, u16* __restrict__ Wqb,
                                             const float* __restrict__ Wo, u16* __restrict__ Wob){
  int bid = blockIdx.x;
  const float* src; u16* dst; int base;
  if(bid < 2048){ src = WE; dst = WEb; base = bid*1024; }
  else if(bid < 2112){ src = Wq; dst = Wqb; base = (bid-2048)*1024; }
  else { src = Wo; dst = Wob; base = (bid-2112)*1024; }
  int i = base + threadIdx.x*4;
  float4 v = *(const float4*)(src + i);
  ushort4 o; o.x = f2bf(v.x); o.y = f2bf(v.y); o.z = f2bf(v.z); o.w = f2bf(v.w);
  *(ushort4*)(dst + i) = o;
}

// ================= K1: qkvvT[b][oc][n] = sum_c Wq[oc][c]*x[b][c][n] (MFMA) =========
#define K1PAD 136
__global__ __launch_bounds__(256) void k1_qkvv(const float* __restrict__ x, const u16* __restrict__ Wqb, u16* __restrict__ qkvvT){
  __shared__ u16 lB[128*K1PAD];
  const int tile = blockIdx.x;            // b*256 + token tile
  const int b  = tile >> 8;
  const int n0 = (tile & 255) << 7;
  const int tid = threadIdx.x;
  const float* xb = x + (size_t)b*128*32768;
  {
    const int cb = (tid >> 4) << 1;       // even channel 0..30
    const int m  = tid & 15;
    const int t8 = m << 3;                // 8-token block
    const int swz = (m & 3) << 3;         // rotation amount (u16 units)
    unsigned int* basep = (unsigned int*)lB;
    #pragma unroll
    for(int r=0;r<4;++r){
      const int c = cb + (r<<5);
      const float4* p0 = (const float4*)(xb + (size_t)c*32768 + n0 + t8);
      const float4* p1 = (const float4*)(xb + (size_t)(c+1)*32768 + n0 + t8);
      float4 a0 = p0[0], a1 = p0[1];
      float4 b0 = p1[0], b1 = p1[1];
      const int rot = (swz + c) & 127;    // rotation keeps everything inside the row
      int di = t8*68 + (rot>>1);
      basep[di      ] = pk2(a0.x, b0.x);
      basep[di+  68 ] = pk2(a0.y, b0.y);
      basep[di+ 136 ] = pk2(a0.z, b0.z);
      basep[di+ 204 ] = pk2(a0.w, b0.w);
      basep[di+ 272 ] = pk2(a1.x, b1.x);
      basep[di+ 340 ] = pk2(a1.y, b1.y);
      basep[di+ 408 ] = pk2(a1.z, b1.z);
      basep[di+ 476 ] = pk2(a1.w, b1.w);
    }
  }
  __syncthreads();
  const int wave = tid >> 6, lane = tid & 63;
  const int wm = (wave & 1) << 6;   // oc half
  const int wn = (wave >> 1) << 6;  // token half
  const int lm = lane & 15, lq = lane >> 4;
  u16* outb = qkvvT + (size_t)b*512*32768;
  for(int s=0;s<4;++s){
    const int oc0 = s << 7;
    f32x4 acc[4][4] = {};
    const u16* Arow = Wqb + (oc0 + wm + lm)*128 + lq*8;
    #pragma unroll
    for(int ks=0; ks<4; ++ks){
      bf16x8 af[4], bfr[4];
      #pragma unroll
      for(int mt=0;mt<4;++mt) af[mt] = *(const bf16x8*)(Arow + mt*2048 + ks*32);
      #pragma unroll
      for(int nt=0;nt<4;++nt){
        const int tr = wn + nt*16 + lm;
        const int rot = ((((tr>>3)&3)<<3) + ks*32 + lq*8) & 127;
        bfr[nt] = *(const bf16x8*)(&lB[tr*K1PAD + rot]);
      }
      #pragma unroll
      for(int mt=0;mt<4;++mt)
        #pragma unroll
        for(int nt=0;nt<4;++nt)
          acc[mt][nt] = MFMA16(af[mt], bfr[nt], acc[mt][nt]);
    }
    #pragma unroll
    for(int mt=0;mt<4;++mt){
      const int ocr = oc0 + wm + mt*16 + lq*4;
      #pragma unroll
      for(int nt=0;nt<4;++nt){
        const int n = n0 + wn + nt*16 + lm;
        #pragma unroll
        for(int r=0;r<4;++r) outb[(size_t)(ocr+r)*32768 + n] = f2bf(acc[mt][nt][r]);
      }
    }
  }
}

// ============ K2: fold fc(1x1) into depthwise-grouped conv weights ===============
// W_eff2 layout: [g 32][j 16][k 27][ol 4][dup 2] fp32 — each weight DUPLICATED
// (w,w) so the conv role's packed-FP32 FMA gets a ready (w,w) operand pair.
__global__ void k2_weff(const float* __restrict__ Wdep, const float* __restrict__ Wfc,
                        const float* __restrict__ bdep, const float* __restrict__ bfc,
                        float* __restrict__ W_eff2, float* __restrict__ bias_eff){
  int idx = blockIdx.x*256 + threadIdx.x;
  if(idx < 55296){
    int ol = idx & 3;
    int k  = (idx >> 2) % 27;
    int j  = (idx / 108) & 15;
    int g  = idx / 1728;
    int oc = g*4 + ol;
    float s = 0.f;
    for(int o=0;o<16;++o) s += Wdep[(oc*16 + o)*27 + k] * Wfc[o*16 + j];
    W_eff2[idx*2] = s;
    W_eff2[idx*2+1] = s;
  }
  if(idx < 128){
    float s = bdep[idx];
    for(int o=0;o<16;++o){
      float wsum = 0.f;
      for(int k=0;k<27;++k) wsum += Wdep[(idx*16 + o)*27 + k];
      s += wsum * bfc[o];  // b_fc == 0 in this problem (boundary fold vacuous)
    }
    bias_eff[idx] = s;
  }
}

// ============ KMEGA: kconv + k2b(norms) + k3(proj) + k4(gram) in ONE launch ======
// kconv role: packed-FP32 with DUAL LDS tile copies. r7 lesson: shifted pairs
// (fa.y,fa.z) are odd-aligned VGPR pairs -> VOP3P needs even-aligned 64b pairs
// -> compiler rematerialized them as unaligned LDS re-reads (conflicts 2.8e7 ->
// 6.55e7, eating the whole pk gain). Fix: stage copy B[j]=A[j+1]; all 12 pairs
// per row are then plain aligned f32x2 loads (pA[0..4] from A, pB[0..3] from B)
// — no swizzle syntax (r8/r9 container failures: suspected ICE on .lo/.hi
// initializer lists; this variant is semantically identical without them).
#define CSX 36
#define CSZ 360            // 10*CSX
#define LFB 3600           // float offset of shifted copy B
__global__ __launch_bounds__(256,4) void kmega(const u16* __restrict__ qkvvT, const float* __restrict__ W_eff2,
                                               const float* __restrict__ bias_eff, u16* __restrict__ convo,
                                               const u16* __restrict__ WEb, float* __restrict__ kp,
                                               float* __restrict__ vp, float* __restrict__ G,
                                               float* __restrict__ invn){
  __shared__ float lf[2*10*CSZ];   // 28,800 B (kconv role: copy A + shifted copy B)
  __shared__ float wsum[4];        // k2b role
  const int bid = blockIdx.x;
  const int gq = bid / 15, rr = bid - gq*15;
  const int tid = threadIdx.x;

  if(rr < 8){
    // ---------------- kconv role (cidx 0..2047), packed fp32, dual-copy ----------
    const int cidx = gq*8 + rr;
    const int gx = cidx & 15, g = (cidx>>4)&31, b = cidx>>9;
    const int zt = gx >> 2, yt = gx & 3;
    const int z0 = zt << 3, y0 = yt << 3;
    const int lz = tid >> 5;                // output z (0..7)
    const int vy = (tid >> 2) & 7;
    const int x0 = (tid & 3) << 3;
    f32x2 acc2[4][4];
    #pragma unroll
    for(int oc=0;oc<4;++oc)
      #pragma unroll
      for(int xp=0;xp<4;++xp) acc2[oc][xp] = (f32x2){0.f, 0.f};
    const u16* qb = qkvvT + (size_t)b*512*32768;
    const int sz = tid / 10, sy = tid - sz*10;
    const int gz = z0 + sz - 1, gy = y0 + sy - 1;
    const bool srow_ok = (tid < 100) && ((unsigned)gz < 32u) && ((unsigned)gy < 32u);
    float2* d2  = (float2*)&lf[sz*CSZ + sy*CSX];
    float2* d2B = (float2*)&lf[LFB + sz*CSZ + sy*CSX];
    const float* Wgbase = W_eff2 + (size_t)(g*16)*216;

    for(int p=0;p<16;++p){
      __syncthreads();   // previous pass compute done
      if(tid < 100){
        if(srow_ok){
          const u16* src = qb + ((size_t)(p*32 + g))*32768 + gz*1024 + gy*32;
          float carry = 0.f;
          #pragma unroll
          for(int q=0;q<4;++q){
            bf16x8 v = *(const bf16x8*)(src + q*8);
            float w0=bf2f((u16)v[0]), w1=bf2f((u16)v[1]), w2=bf2f((u16)v[2]), w3=bf2f((u16)v[3]);
            float w4=bf2f((u16)v[4]), w5=bf2f((u16)v[5]), w6=bf2f((u16)v[6]), w7=bf2f((u16)v[7]);
            d2[q*4+0] = make_float2(carry, w0);
            d2[q*4+1] = make_float2(w1, w2);
            d2[q*4+2] = make_float2(w3, w4);
            d2[q*4+3] = make_float2(w5, w6);
            d2B[q*4+0] = make_float2(w0, w1);
            d2B[q*4+1] = make_float2(w2, w3);
            d2B[q*4+2] = make_float2(w4, w5);
            d2B[q*4+3] = make_float2(w6, w7);
            carry = w7;
          }
          d2[16]  = make_float2(carry, 0.f);
          d2B[16] = make_float2(0.f, 0.f);
        } else {
          #pragma unroll
          for(int i=0;i<17;++i){ d2[i] = make_float2(0.f, 0.f); d2B[i] = make_float2(0.f, 0.f); }
        }
      }
      __syncthreads();
      const float* Wg = Wgbase + p*216;    // [kz3][ky3][kx3][oc4][dup2], wave-uniform
      #pragma unroll
      for(int dy=0;dy<3;++dy){
        #pragma unroll
        for(int dz=0;dz<3;++dz){
          const int rbase = (lz+dz)*CSZ + (vy+dy)*CSX + x0;
          const f32x2* pA = (const f32x2*)&lf[rbase];          // aligned pairs
          const f32x2* pB = (const f32x2*)&lf[LFB + rbase];    // shifted copy
          f32x2 fpl[4] = {pA[0], pA[1], pA[2], pA[3]};         // kx=0 taps
          f32x2 fsl[4] = {pB[0], pB[1], pB[2], pB[3]};         // kx=1 taps
          f32x2 fph[4] = {pA[1], pA[2], pA[3], pA[4]};         // kx=2 taps
          const f32x2* Wb = (const f32x2*)Wg + (dz*3+dy)*12;   // [kx3][oc4] (w,w) pairs
          #pragma unroll
          for(int xp=0;xp<4;++xp){
            f32x2 f0 = fpl[xp], f1 = fsl[xp], f2 = fph[xp];
            acc2[0][xp] += Wb[0]*f0;  acc2[1][xp] += Wb[1]*f0;
            acc2[2][xp] += Wb[2]*f0;  acc2[3][xp] += Wb[3]*f0;
            acc2[0][xp] += Wb[4]*f1;  acc2[1][xp] += Wb[5]*f1;
            acc2[2][xp] += Wb[6]*f1;  acc2[3][xp] += Wb[7]*f1;
            acc2[0][xp] += Wb[8]*f2;  acc2[1][xp] += Wb[9]*f2;
            acc2[2][xp] += Wb[10]*f2; acc2[3][xp] += Wb[11]*f2;
          }
        }
      }
    }
    const float4 bi = *(const float4*)(bias_eff + g*4);  // wave-uniform -> s_load
    const int nb = (z0 + lz)*1024 + (y0+vy)*32 + x0;
    u16* ob = convo + ((size_t)b*32768 + nb)*128 + g*4;
    #pragma unroll
    for(int xi=0;xi<8;++xi){
      unsigned long long pk = (unsigned long long)f2bf(acc2[0][xi>>1][xi&1] + bi.x)
                            | ((unsigned long long)f2bf(acc2[1][xi>>1][xi&1] + bi.y) << 16)
                            | ((unsigned long long)f2bf(acc2[2][xi>>1][xi&1] + bi.z) << 32)
                            | ((unsigned long long)f2bf(acc2[3][xi>>1][xi&1] + bi.w) << 48);
      *(unsigned long long*)(ob + (size_t)xi*128) = pk;
    }
    return;
  }

  const int oidx = gq*7 + (rr - 8);   // 0..1791
  if(oidx < 512){
    // ---------------- k3 role: k_proj / v_SA_proj ----------------
    const int kc = oidx & 31;
    const int b  = (oidx >> 5) & 3;
    const int zz = oidx >> 7;             // 0..3
    const int ts = zz >> 1;
    const int rh = (zz & 1) << 6;
    const int wave = tid >> 6, lane = tid & 63;
    const int lm = lane & 15, lq = lane >> 4;
    const int coff = ts ? 384 : 128;
    const u16* Arow = qkvvT + ((size_t)b*512 + coff + rh + wave*16 + lm)*32768 + kc*1024 + lq*8;
    f32x4 acc[4] = {};
    for(int ks=0; ks<32; ++ks){
      bf16x8 af = *(const bf16x8*)(Arow + ks*32);
      #pragma unroll
      for(int nt=0;nt<4;++nt){
        bf16x8 bfr = *(const bf16x8*)(WEb + (size_t)(nt*16 + lm)*32768 + kc*1024 + ks*32 + lq*8);
        acc[nt] = MFMA16(af, bfr, acc[nt]);
      }
    }
    float* out = (ts ? vp : kp) + (size_t)b*128*64;
    const int r0 = rh + wave*16 + lq*4;
    #pragma unroll
    for(int nt=0;nt<4;++nt){
      const int p = nt*16 + lm;
      #pragma unroll
      for(int r=0;r<4;++r) atomicAdd(&out[(r0+r)*64 + p], acc[nt][r]);
    }
  } else if(oidx < 768){
    // ---------------- k4 role: Gram, one kc chunk per wave ----------------
    const int idx2 = oidx - 512;          // 0..255
    const int h = idx2 & 3, b = (idx2>>2)&3, kcg = idx2 >> 4;   // kcg 0..15
    const int wave = tid >> 6, lane = tid & 63;
    const int kc = kcg*4 + wave;          // 0..63
    const int lm = lane & 15, lq = lane >> 4;
    const u16* qb = qkvvT + ((size_t)b*512 + h*32)*32768 + kc*512 + lq*8;
    const u16* kb = qb + (size_t)128*32768;
    f32x4 acc[2][2] = {};
    for(int ks=0; ks<16; ++ks){
      bf16x8 af[2], bfr[2];
      af[0]  = *(const bf16x8*)(qb + (size_t)lm*32768 + ks*32);
      af[1]  = *(const bf16x8*)(qb + (size_t)(16+lm)*32768 + ks*32);
      bfr[0] = *(const bf16x8*)(kb + (size_t)lm*32768 + ks*32);
      bfr[1] = *(const bf16x8*)(kb + (size_t)(16+lm)*32768 + ks*32);
      #pragma unroll
      for(int mt=0;mt<2;++mt)
        #pragma unroll
        for(int nt=0;nt<2;++nt) acc[mt][nt] = MFMA16(af[mt], bfr[nt], acc[mt][nt]);
    }
    float* Gb = G + (size_t)(b*4 + h)*1024;
    #pragma unroll
    for(int mt=0;mt<2;++mt)
      #pragma unroll
      for(int nt=0;nt<2;++nt)
        #pragma unroll
        for(int r=0;r<4;++r){
          int d = mt*16 + lq*4 + r, e = nt*16 + lm;
          atomicAdd(&Gb[d*32 + e], acc[mt][nt][r]);
        }
  } else {
    // ---------------- k2b role: inverse l2 norms ----------------
    const int idx4 = oidx - 768;          // 0..1023
    const int b = idx4 >> 8, c = idx4 & 255;
    const u16* row = qkvvT + ((size_t)b*512 + c)*32768;
    float s = 0.f;
    for(int n = tid*8; n < 32768; n += 2048){
      bf16x8 v = *(const bf16x8*)(row + n);
      #pragma unroll
      for(int j=0;j<8;++j){ float f = bf2f((u16)v[j]); s += f*f; }
    }
    for(int off=32; off; off>>=1) s += __shfl_down(s, off, 64);
    if((tid & 63)==0) wsum[tid>>6] = s;
    __syncthreads();
    if(tid==0){
      float t = wsum[0]+wsum[1]+wsum[2]+wsum[3];
      invn[idx4] = 1.0f / fmaxf(sqrtf(t), 1e-12f);
    }
  }
}

// ============ K4b: scale+softmax(attn_CA) then M2 = W_out2 * attn_CA =============
__global__ __launch_bounds__(256) void k4b_softmax_m2(const float* __restrict__ G, const float* __restrict__ invn,
                                                      const float* __restrict__ temp, const float* __restrict__ Wout2,
                                                      u16* __restrict__ M2){
  const int b = blockIdx.x >> 2, h = blockIdx.x & 3;
  __shared__ float A[32][33];
  const float* Gb = G + (size_t)(b*4 + h)*1024;
  const float* inb = invn + b*256;
  const float th = temp[h];
  const int tid = threadIdx.x;
  if(tid < 32){
    const int d = tid;
    const float iq = inb[h*32 + d];
    float row[32]; float mx = -1e30f;
    #pragma unroll
    for(int e=0;e<32;++e){
      float v = Gb[d*32+e] * iq * inb[128 + h*32 + e] * th;
      row[e] = v; mx = fmaxf(mx, v);
    }
    float s = 0.f;
    #pragma unroll
    for(int e=0;e<32;++e){ float ee = __expf(row[e]-mx); row[e] = ee; s += ee; }
    const float rs = 1.0f/s;
    #pragma unroll
    for(int e=0;e<32;++e) A[d][e] = row[e]*rs;
  }
  __syncthreads();
  for(int o = tid; o < 2048; o += 256){
    const int j = o >> 5, e = o & 31;
    float s = 0.f;
    #pragma unroll
    for(int d=0;d<32;++d) s += Wout2[j*128 + h*32 + d] * A[d][e];
    M2[((size_t)b*64 + j)*128 + h*32 + e] = f2bf(s);
  }
}

// ============ K5 v3: Linformer attention via MFMA ================================
__global__ __launch_bounds__(256) void k5_xsa(const u16* __restrict__ qkvvT, const float* __restrict__ kp,
                                              const float* __restrict__ vp, const float* __restrict__ invn,
                                              const float* __restrict__ bE, const float* __restrict__ temp2,
                                              u16* __restrict__ xsa){
  __shared__ __align__(16) u16 L[14336];
  __shared__ float liqt[32];
  u16* lkAh = L;            // [64][40] : kp^T + bE, hi
  u16* lkAl = L + 2560;     // lo
  u16* lvAh = L + 5120;     // [32][72] : vp + bE, hi
  u16* lvAl = L + 7424;     // lo
  u16* Pl   = L + 9728;     // [4 waves][16][72] per-wave P bounce
  const int b = blockIdx.z, h = blockIdx.y;
  const int tid = threadIdx.x;
  const float t2 = temp2[h];
  {  // stage lkA = kp^T + bE (hi/lo)
    const int p = tid >> 2, d8 = (tid & 3) << 3;
    const float be = bE[p];
    const float* kpb = kp + ((size_t)b*128 + h*32)*64;
    #pragma unroll
    for(int j=0;j<8;++j){
      float v = kpb[(size_t)(d8+j)*64 + p] + be;
      u16 hi = f2bf(v);
      lkAh[p*40 + d8 + j] = hi;
      lkAl[p*40 + d8 + j] = f2bf(v - bf2f(hi));
    }
  }
  {  // stage lvA = vp + bE (hi/lo)
    const int d = tid >> 3, p8 = (tid & 7) << 3;
    const float* vpb = vp + ((size_t)b*128 + h*32)*64;
    #pragma unroll
    for(int j=0;j<8;++j){
      float v = vpb[(size_t)d*64 + p8 + j] + bE[p8+j];
      u16 hi = f2bf(v);
      lvAh[d*72 + p8 + j] = hi;
      lvAl[d*72 + p8 + j] = f2bf(v - bf2f(hi));
    }
  }
  if(tid < 32) liqt[tid] = invn[b*256 + h*32 + tid] * t2;   // fold temp2 into qn
  __syncthreads();
  const int wave = tid >> 6, lane = tid & 63;
  const int lm = lane & 15, lq = lane >> 4;
  const int tokw = blockIdx.x*256 + wave*64;
  const u16* qb = qkvvT + ((size_t)b*512 + h*32)*32768;
  float iq[8];
  #pragma unroll
  for(int j=0;j<8;++j) iq[j] = liqt[lq*8+j];
  u16* PW = Pl + wave*1152 + lm*72;
  u16* ob = xsa + (((size_t)b*4 + h)*32)*32768;
  for(int nt=0; nt<4; ++nt){
    const int tok = tokw + nt*16 + lm;
    union { u16 u[8]; bf16x8 v; } qh, ql;
    #pragma unroll
    for(int j=0;j<8;++j){
      float qv = bf2f(qb[(size_t)(lq*8+j)*32768 + tok]) * iq[j];
      u16 hi = f2bf(qv);
      qh.u[j] = hi;
      ql.u[j] = f2bf(qv - bf2f(hi));
    }
    f32x4 accS[4];
    #pragma unroll
    for(int mt=0;mt<4;++mt){
      bf16x8 Ah = *(const bf16x8*)(lkAh + (mt*16+lm)*40 + lq*8);
      bf16x8 Al = *(const bf16x8*)(lkAl + (mt*16+lm)*40 + lq*8);
      f32x4 a = {};
      a = MFMA16(Ah, qh.v, a);
      a = MFMA16(Ah, ql.v, a);
      a = MFMA16(Al, qh.v, a);
      accS[mt] = a;
    }
    float mx = -1e30f;
    #pragma unroll
    for(int mt=0;mt<4;++mt)
      mx = fmaxf(mx, fmaxf(fmaxf(accS[mt][0],accS[mt][1]), fmaxf(accS[mt][2],accS[mt][3])));
    mx = fmaxf(mx, __shfl_xor(mx,16));
    mx = fmaxf(mx, __shfl_xor(mx,32));
    float pexp[4][4];
    float sum = 0.f;
    #pragma unroll
    for(int mt=0;mt<4;++mt)
      #pragma unroll
      for(int r=0;r<4;++r){ float e = __expf(accS[mt][r]-mx); pexp[mt][r]=e; sum+=e; }
    sum += __shfl_xor(sum,16);
    sum += __shfl_xor(sum,32);
    const float rinv = 1.0f/sum;
    #pragma unroll
    for(int mt=0;mt<4;++mt){
      *(unsigned int*)(PW + mt*16 + lq*4)     = pk2(pexp[mt][0], pexp[mt][1]);
      *(unsigned int*)(PW + mt*16 + lq*4 + 2) = pk2(pexp[mt][2], pexp[mt][3]);
    }
    f32x4 accO[2] = {};
    #pragma unroll
    for(int ks=0;ks<2;++ks){
      bf16x8 Pb = *(const bf16x8*)(PW + ks*32 + lq*8);
      #pragma unroll
      for(int mt=0;mt<2;++mt){
        bf16x8 Avh = *(const bf16x8*)(lvAh + (mt*16+lm)*72 + ks*32 + lq*8);
        bf16x8 Avl = *(const bf16x8*)(lvAl + (mt*16+lm)*72 + ks*32 + lq*8);
        accO[mt] = MFMA16(Avh, Pb, accO[mt]);
        accO[mt] = MFMA16(Avl, Pb, accO[mt]);
      }
    }
    #pragma unroll
    for(int mt=0;mt<2;++mt)
      #pragma unroll
      for(int r=0;r<4;++r)
        ob[(size_t)(mt*16+lq*4+r)*32768 + tok] = f2bf(accO[mt][r]*rinv);
  }
}

// ============ K6: output assembly (SA gather-GEMM + CA GEMM + conv + rates), fp32 out
#define K6PAD 136
__global__ __launch_bounds__(256) void k6_out(const u16* __restrict__ qkvvT, const u16* __restrict__ xsa,
                                              const u16* __restrict__ conv, const u16* __restrict__ M2,
                                              const u16* __restrict__ Woutb, const float* __restrict__ bout,
                                              const float* __restrict__ bout2, const float* __restrict__ rate,
                                              const float* __restrict__ rate2, float* __restrict__ out){
  __shared__ u16 lA[128*K6PAD];
  const int tile = blockIdx.x;
  const int b  = tile >> 8;
  const int n0 = (tile & 255) << 7;
  const int tid = threadIdx.x;
  const int hh = (n0 >> 8) & 3;   // constant per 128-token tile
  const int dh = n0 >> 10;
  // ---- phase A: stage scrambled x_SA segment (contiguous!) -> lA[tok][c']
  const u16* xseg = xsa + (((size_t)b*4 + hh)*32 + dh)*32768 + ((size_t)(n0 & 255) << 7);
  {
    const int r = tid >> 1, off = (tid & 1) << 6;
    const u16* src = xseg + r*128 + off;
    u16* dst = &lA[r*K6PAD + off];
    #pragma unroll
    for(int q=0;q<8;++q) *(bf16x8*)(dst + q*8) = *(const bf16x8*)(src + q*8);
  }
  __syncthreads();
  const int wave = tid >> 6, lane = tid & 63;
  const int lm = lane & 15, lq = lane >> 4;
  f32x4 accS[2][4] = {};
  #pragma unroll
  for(int ks=0;ks<4;++ks){
    bf16x8 a0 = *(const bf16x8*)(&lA[(wave*32 + lm)*K6PAD + ks*32 + lq*8]);
    bf16x8 a1 = *(const bf16x8*)(&lA[(wave*32 + 16 + lm)*K6PAD + ks*32 + lq*8]);
    #pragma unroll
    for(int nt=0;nt<4;++nt){
      bf16x8 bw = *(const bf16x8*)(Woutb + (nt*16 + lm)*128 + ks*32 + lq*8);
      accS[0][nt] = MFMA16(a0, bw, accS[0][nt]);
      accS[1][nt] = MFMA16(a1, bw, accS[1][nt]);
    }
  }
  __syncthreads();
  // ---- phase B: stage v_CA tile transposed -> lA[tok][c'']
  {
    const int cb = tid >> 4, t8 = (tid & 15) << 3;
    const u16* vb = qkvvT + ((size_t)b*512 + 256)*32768 + n0;
    #pragma unroll
    for(int r2=0;r2<8;++r2){
      int c = cb + (r2<<4);
      bf16x8 v = *(const bf16x8*)(vb + (size_t)c*32768 + t8);
      #pragma unroll
      for(int j=0;j<8;++j) lA[(t8+j)*K6PAD + c] = (u16)v[j];
    }
  }
  __syncthreads();
  f32x4 accC[2][4] = {};
  #pragma unroll
  for(int ks=0;ks<4;++ks){
    bf16x8 a0 = *(const bf16x8*)(&lA[(wave*32 + lm)*K6PAD + ks*32 + lq*8]);
    bf16x8 a1 = *(const bf16x8*)(&lA[(wave*32 + 16 + lm)*K6PAD + ks*32 + lq*8]);
    #pragma unroll
    for(int nt=0;nt<4;++nt){
      bf16x8 bm = *(const bf16x8*)(M2 + ((size_t)b*64 + nt*16 + lm)*128 + ks*32 + lq*8);
      accC[0][nt] = MFMA16(a0, bm, accC[0][nt]);
      accC[1][nt] = MFMA16(a1, bm, accC[1][nt]);
    }
  }
  const float rt = rate[0], rt2 = rate2[0];
  float* ob = out + ((size_t)b*32768 + n0)*128;
  const u16* cbp = conv + ((size_t)b*32768 + n0)*128;
  #pragma unroll
  for(int mt=0;mt<2;++mt){
    #pragma unroll
    for(int r=0;r<4;++r){
      const int tok = wave*32 + mt*16 + lq*4 + r;
      #pragma unroll
      for(int nt=0;nt<4;++nt){
        const int j = nt*16 + lm;
        float sa = accS[mt][nt][r] + bout[j];
        float ca = accC[mt][nt][r] + bout2[j];
        float c1 = bf2f(cbp[(size_t)tok*128 + j]);
        float c2 = bf2f(cbp[(size_t)tok*128 + 64 + j]);
        ob[(size_t)tok*128 + j]      = rt*sa + rt2*c1;
        ob[(size_t)tok*128 + 64 + j] = rt*ca + rt2*c2;
      }
    }
  }
}

extern "C" void kernel_launch(void* const* d_in, const int* in_sizes, int n_in,
                              void* d_out, int out_size, void* d_ws, size_t ws_size,
                              hipStream_t stream){
  const float* x     = (const float*)d_in[0];
  const float* Wq    = (const float*)d_in[1];
  const float* Wfc   = (const float*)d_in[2];
  const float* bfc   = (const float*)d_in[3];
  const float* Wdep  = (const float*)d_in[4];
  const float* bdep  = (const float*)d_in[5];
  const float* WE    = (const float*)d_in[6];
  const float* bE    = (const float*)d_in[7];
  const float* temp  = (const float*)d_in[8];
  const float* temp2 = (const float*)d_in[9];
  const float* rate  = (const float*)d_in[10];
  const float* rate2 = (const float*)d_in[11];
  const float* Wout  = (const float*)d_in[12];
  const float* bout  = (const float*)d_in[13];
  const float* Wout2 = (const float*)d_in[14];
  const float* bout2 = (const float*)d_in[15];
  float* outp = (float*)d_out;

  char* w = (char*)d_ws;
  size_t off = 0;
  auto alloc = [&](size_t bytes)->char*{ char* p = w + off; off += (bytes + 255) & ~(size_t)255; return p; };
  u16*   qkvvT  = (u16*)  alloc((size_t)4*512*32768*2);   // 134 MB, channel-major
  u16*   xsa    = (u16*)  alloc((size_t)4*4*32*32768*2);  // 33.5 MB
  u16*   convb  = (u16*)  alloc((size_t)4*32768*128*2);   // 33.5 MB, token-major
  float* W_eff2 = (float*)alloc(110592*4);                // duplicated (w,w) pairs
  float* biasef = (float*)alloc(128*4);
  float* invn   = (float*)alloc(1024*4);
  float* kp     = (float*)alloc(32768*4);
  float* vp     = (float*)alloc(32768*4);
  float* G      = (float*)alloc(16384*4);
  u16*   M2     = (u16*)  alloc(32768*2);
  u16*   WEb    = (u16*)  alloc((size_t)2097152*2);       // bf16 copies of MFMA weights
  u16*   Wqb    = (u16*)  alloc(65536*2);
  u16*   Woutb  = (u16*)  alloc(8192*2);

  // zero the fp32 atomic-accumulation buffers (kp|vp|G are contiguous)
  hipMemsetAsync(kp, 0, (size_t)(32768+32768+16384)*4, stream);

  kcvt3         <<<2120,          256, 0, stream>>>(WE, WEb, Wq, Wqb, Wout, Woutb);
  k1_qkvv       <<<1024,          256, 0, stream>>>(x, Wqb, qkvvT);
  k2_weff       <<<216,           256, 0, stream>>>(Wdep, Wfc, bdep, bfc, W_eff2, biasef);
  kmega         <<<3840,          256, 0, stream>>>(qkvvT, W_eff2, biasef, convb, WEb, kp, vp, G, invn);
  k4b_softmax_m2<<<16,            256, 0, stream>>>(G, invn, temp, Wout2, M2);
  k5_xsa        <<<dim3(128,4,4), 256, 0, stream>>>(qkvvT, kp, vp, invn, bE, temp2, xsa);
  k6_out        <<<1024,          256, 0, stream>>>(qkvvT, xsa, convb, M2, Woutb, bout, bout2, rate, rate2, outp);
}